// Round 2
// baseline (41086.334 us; speedup 1.0000x reference)
//
#include <hip/hip_runtime.h>
#include <hip/hip_bf16.h>
#include <cstddef>

// Problem constants
#define B_  256
#define T_  256
#define D_  256
#define H_  384
#define G_  1542
#define L_  3
#define CH_ 128
#define K_  10
#define HS_ 64
#define NBS 257      // blocks in persistent serial kernel (257*6 = 1542)
#define GPB 6        // gate columns per block

using bf16x8 = __attribute__((ext_vector_type(8))) short;
using f32x4  = __attribute__((ext_vector_type(4))) float;

__device__ __forceinline__ float sigf(float x) { return 1.f / (1.f + expf(-x)); }
__device__ __forceinline__ float bf2f(unsigned short s) {
    return __uint_as_float(((unsigned)s) << 16);
}
__device__ __forceinline__ unsigned short f2bf(float f) {
    unsigned u = __float_as_uint(f);
    return (unsigned short)((u + 0x7fffu + ((u >> 16) & 1u)) >> 16);
}

// ---------------- zero ----------------
__global__ void k_zero(float* __restrict__ p, int n) {
    int i = blockIdx.x * blockDim.x + threadIdx.x;
    if (i < n) p[i] = 0.f;
}

// ---------------- x transpose: xT[t][d][b] (bf16) ----------------
__global__ __launch_bounds__(256)
void k_xt(const float* __restrict__ x, unsigned short* __restrict__ xT) {
    __shared__ float tl[64][65];
    const int t = blockIdx.x;
    const int d0 = blockIdx.y * 64, b0 = blockIdx.z * 64;
    const int lane = threadIdx.x & 63, r4 = threadIdx.x >> 6;
    #pragma unroll
    for (int s = 0; s < 16; ++s) {
        int row = r4 + s * 4;   // b within tile
        tl[row][lane] = x[((size_t)(b0 + row) * T_ + t) * D_ + d0 + lane];
    }
    __syncthreads();
    #pragma unroll
    for (int s = 0; s < 16; ++s) {
        int dd = r4 + s * 4;    // d within tile
        xT[((size_t)t * D_ + d0 + dd) * B_ + b0 + lane] = f2bf(tl[lane][dd]);
    }
}

// ---------------- pack serial weights: Wser[g][640], biasv[g] ----------------
__global__ void k_pack(const float* __restrict__ Wk, const float* __restrict__ bk,
                       const float* __restrict__ Wr, const float* __restrict__ br,
                       float* __restrict__ Wser, float* __restrict__ biasv) {
    int idx = blockIdx.x * 256 + threadIdx.x;
    const int WN = G_ * 640;
    if (idx < WN) {
        int g = idx / 640, i = idx % 640;
        Wser[idx] = (i < 256) ? Wk[(size_t)i * G_ + g] : Wr[(size_t)(i - 256) * G_ + g];
    } else {
        int g = idx - WN;
        if (g < G_)
            biasv[g] = bk[g] + br[g] + Wk[(size_t)256 * G_ + g] + Wr[(size_t)384 * G_ + g];
    }
}

// ---------------- conv weights: Wg[o][k*384+h] (bf16) ----------------
__global__ void k_wg(const float* __restrict__ Wc, unsigned short* __restrict__ Wg) {
    int idx = blockIdx.x * 256 + threadIdx.x;
    if (idx >= H_ * K_ * H_) return;
    int o = idx / (K_ * H_);
    int rem = idx % (K_ * H_);
    int k = rem / H_, h = rem % H_;
    Wg[idx] = f2bf(Wc[((size_t)o * H_ + h) * K_ + k]);
}

// ---------------- grid barrier (all NBS blocks co-resident) ----------------
__device__ __forceinline__ void gbar(int* cnt, int& tgt) {
    __threadfence();
    __syncthreads();
    if (threadIdx.x == 0) {
        atomicAdd(cnt, 1);
        while (atomicAdd(cnt, 0) < tgt) __builtin_amdgcn_s_sleep(4);
    }
    __syncthreads();
    __threadfence();
    tgt += NBS;
}

// ---------------- persistent serial recurrence ----------------
// Phase A (per step): xoT[g][b] = bias[g] + sum_i in640 a[i][b]*Wser[g][i]
//   a = concat(x_t (bf16), h_{t-1} (fp32)); block owns 6 g's, thread = b.
// Phase B: gates -> cT, hT (fp32 ping-pong), hbf[t][b][h] (bf16), dis.
__global__ __launch_bounds__(256, 2)
void k_serial(const unsigned short* __restrict__ xT, const float* __restrict__ Wser,
              const float* __restrict__ biasv, float* __restrict__ hT,
              float* __restrict__ cT, float* __restrict__ xoT,
              unsigned short* __restrict__ hbf, float* __restrict__ dis,
              int* __restrict__ bar)
{
    __shared__ __align__(16) float Wl[GPB][640];
    __shared__ float bl[GPB];
    const int j = blockIdx.x, tid = threadIdx.x;
    const int g0 = j * GPB;
    for (int idx = tid; idx < GPB * 640; idx += 256)
        Wl[idx / 640][idx % 640] = Wser[(size_t)g0 * 640 + idx];
    if (tid < GPB) bl[tid] = biasv[g0 + tid];
    __syncthreads();

    int tgt = NBS;
    const int b = tid;
    for (int t = 0; t < T_; ++t) {
        // ---- Phase A: GEMM ----
        float acc[GPB];
        #pragma unroll
        for (int gg = 0; gg < GPB; ++gg) acc[gg] = bl[gg];
        const unsigned short* xr = xT + (size_t)t * D_ * B_ + b;
        const float* hp = hT + ((t + 1) & 1) * (H_ * B_) + b;
        for (int i0 = 0; i0 < D_; i0 += 4) {
            float a0 = bf2f(xr[(i0 + 0) * B_]);
            float a1 = bf2f(xr[(i0 + 1) * B_]);
            float a2 = bf2f(xr[(i0 + 2) * B_]);
            float a3 = bf2f(xr[(i0 + 3) * B_]);
            #pragma unroll
            for (int gg = 0; gg < GPB; ++gg) {
                float4 w = *(const float4*)&Wl[gg][i0];
                acc[gg] = fmaf(a3, w.w, fmaf(a2, w.z, fmaf(a1, w.y, fmaf(a0, w.x, acc[gg]))));
            }
        }
        for (int i0 = 0; i0 < H_; i0 += 4) {
            float a0 = hp[(i0 + 0) * B_];
            float a1 = hp[(i0 + 1) * B_];
            float a2 = hp[(i0 + 2) * B_];
            float a3 = hp[(i0 + 3) * B_];
            #pragma unroll
            for (int gg = 0; gg < GPB; ++gg) {
                float4 w = *(const float4*)&Wl[gg][256 + i0];
                acc[gg] = fmaf(a3, w.w, fmaf(a2, w.z, fmaf(a1, w.y, fmaf(a0, w.x, acc[gg]))));
            }
        }
        #pragma unroll
        for (int gg = 0; gg < GPB; ++gg) xoT[(g0 + gg) * B_ + b] = acc[gg];

        gbar(bar, tgt);

        // ---- Phase B: gates ----
        #pragma unroll
        for (int e = 0; e < 2; ++e) {
            int idx = e * (NBS * 256) + j * 256 + tid;
            if (idx < B_ * H_) {
                int hh = idx >> 8, bb = idx & 255;
                float z0 = xoT[0 * B_ + bb], z1 = xoT[1 * B_ + bb], z2 = xoT[2 * B_ + bb];
                float z3 = xoT[3 * B_ + bb], z4 = xoT[4 * B_ + bb], z5 = xoT[5 * B_ + bb];
                float m1 = fmaxf(fmaxf(z0, z1), z2);
                float e0 = expf(z0 - m1), e1 = expf(z1 - m1), e2 = expf(z2 - m1);
                float s1 = e0 + e1 + e2;
                float fm0 = e0 / s1, fm1 = (e0 + e1) / s1;
                float m2 = fmaxf(fmaxf(z3, z4), z5);
                float f3 = expf(z3 - m2), f4 = expf(z4 - m2), f5 = expf(z5 - m2);
                float s2 = f3 + f4 + f5;
                float im1 = (f4 + f5) / s2, im2 = f5 / s2;

                int l = hh >> 7;
                float fm = (l == 0) ? fm0 : (l == 1) ? fm1 : 1.f;
                float im = (l == 0) ? 1.f : (l == 1) ? im1 : im2;

                float fg = sigf(xoT[(6 + hh) * B_ + bb]);
                float ig = sigf(xoT[(6 + H_ + hh) * B_ + bb]);
                float og = sigf(xoT[(6 + 2 * H_ + hh) * B_ + bb]);
                float ci = tanhf(xoT[(6 + 3 * H_ + hh) * B_ + bb]);

                float cl = cT[idx];
                float ov = fm * im;
                float cn = ov * (fg * cl + ig * ci) + (fm - ov) * cl + (im - ov) * ci;
                float hn = og * tanhf(cn);

                cT[idx] = cn;
                hT[(t & 1) * (H_ * B_) + idx] = hn;
                hbf[((size_t)t * B_ + bb) * H_ + hh] = f2bf(hn);
                if (hh == 0) dis[t * B_ + bb] = 1.f - (fm0 + fm1 + 1.f) * (1.f / 3.f);
            }
        }
        gbar(bar, tgt);
    }
}

// ---------------- ld weights ----------------
__global__ void k_ld(const float* __restrict__ dis_all, float* __restrict__ ld_all)
{
    int t = blockIdx.x, b = threadIdx.x;
    float s = 0.f, sk[K_];
    #pragma unroll
    for (int k = 0; k < K_; ++k) {
        int tau = t - (K_ - 1) + k;
        float d = (tau >= 0) ? dis_all[tau * B_ + b] : 0.f;
        s += d; sk[k] = s;
    }
    float m = sk[0];
    #pragma unroll
    for (int k = 1; k < K_; ++k) m = fmaxf(m, sk[k]);
    float sum = 0.f;
    #pragma unroll
    for (int k = 0; k < K_; ++k) { sk[k] = expf(sk[k] - m); sum += sk[k]; }
    float inv = 1.f / sum;
    #pragma unroll
    for (int k = 0; k < K_; ++k)
        ld_all[((size_t)t * B_ + b) * K_ + k] = sk[k] * inv;
}

// ---------------- conv via MFMA: out_part[b][t][o] = sum_{k,h} ld*h*Wc ----------------
// Block: 64 b x 384 o for one t; 4 waves, wave tile 64x96 (4x6 frags of 16x16).
__global__ __launch_bounds__(256)
void k_conv(const unsigned short* __restrict__ hbf, const float* __restrict__ ld_all,
            const unsigned short* __restrict__ Wg, float* __restrict__ out_part)
{
    __shared__ unsigned short Al[64][40];     // A chunk [b][kk], pad to 40
    __shared__ unsigned short Bl[384][40];    // B chunk [o][kk]
    __shared__ float ldl[64][10];
    const int b0 = blockIdx.x * 64;
    const int t  = blockIdx.y;
    const int tid = threadIdx.x;
    const int wave = tid >> 6, lane = tid & 63;

    for (int idx = tid; idx < 64 * K_; idx += 256)
        ldl[idx / K_][idx % K_] = ld_all[((size_t)t * B_ + b0 + idx / K_) * K_ + idx % K_];
    __syncthreads();

    f32x4 acc[4][6] = {};
    const int arow = tid & 63, ahalf = tid >> 6;

    for (int ch = 0; ch < 120; ++ch) {
        int k = ch / 12, h0 = (ch % 12) * 32;
        int tau = t - (K_ - 1) + k;
        // stage A: 64 x 32
        {
            int4 pk;
            if (tau >= 0) {
                float l = ldl[arow][k];
                const unsigned short* hp =
                    hbf + ((size_t)tau * B_ + b0 + arow) * H_ + h0 + ahalf * 8;
                int4 v = *(const int4*)hp;
                unsigned vv[4] = {(unsigned)v.x, (unsigned)v.y, (unsigned)v.z, (unsigned)v.w};
                unsigned out[4];
                #pragma unroll
                for (int q = 0; q < 4; ++q) {
                    float flo = __uint_as_float(vv[q] << 16) * l;
                    float fhi = __uint_as_float(vv[q] & 0xffff0000u) * l;
                    out[q] = (unsigned)f2bf(flo) | ((unsigned)f2bf(fhi) << 16);
                }
                pk = make_int4((int)out[0], (int)out[1], (int)out[2], (int)out[3]);
            } else {
                pk = make_int4(0, 0, 0, 0);
            }
            *(int4*)&Al[arow][ahalf * 8] = pk;
        }
        // stage B: 384 x 32
        #pragma unroll
        for (int q = 0; q < 6; ++q) {
            int idx = q * 256 + tid;               // < 1536
            int row = idx >> 2, half = idx & 3;
            const unsigned short* wp = Wg + (size_t)row * 3840 + ch * 32 + half * 8;
            *(int4*)&Bl[row][half * 8] = *(const int4*)wp;
        }
        __syncthreads();

        bf16x8 af[4];
        #pragma unroll
        for (int mi = 0; mi < 4; ++mi)
            af[mi] = *(const bf16x8*)&Al[mi * 16 + (lane & 15)][(lane >> 4) * 8];
        #pragma unroll
        for (int ni = 0; ni < 6; ++ni) {
            bf16x8 bfv = *(const bf16x8*)&Bl[wave * 96 + ni * 16 + (lane & 15)][(lane >> 4) * 8];
            #pragma unroll
            for (int mi = 0; mi < 4; ++mi)
                acc[mi][ni] = __builtin_amdgcn_mfma_f32_16x16x32_bf16(af[mi], bfv, acc[mi][ni], 0, 0, 0);
        }
        __syncthreads();
    }
    // write out: D row = (lane>>4)*4+r (b), col = lane&15 (o)
    #pragma unroll
    for (int mi = 0; mi < 4; ++mi) {
        #pragma unroll
        for (int ni = 0; ni < 6; ++ni) {
            int o = wave * 96 + ni * 16 + (lane & 15);
            int brow = b0 + mi * 16 + ((lane >> 4) << 2);
            #pragma unroll
            for (int r = 0; r < 4; ++r)
                out_part[((size_t)(brow + r) * T_ + t) * H_ + o] = acc[mi][ni][r];
        }
    }
}

// ---------------- theme + combine (32-b blocks) ----------------
__global__ __launch_bounds__(256)
void k_theme(const unsigned short* __restrict__ hbf, const float* __restrict__ ld_all,
             const float* __restrict__ Ws, const float* __restrict__ bs,
             const float* __restrict__ Wrs, const float* __restrict__ brs,
             const float* __restrict__ bc, float* __restrict__ out_part)
{
    __shared__ float hbar[32][385];
    __shared__ float us[32][65];
    __shared__ float ldl[32][10];
    const int b0 = blockIdx.x * 32, t = blockIdx.y, tid = threadIdx.x;

    for (int idx = tid; idx < 32 * K_; idx += 256)
        ldl[idx / K_][idx % K_] = ld_all[((size_t)t * B_ + b0 + idx / K_) * K_ + idx % K_];
    __syncthreads();

    for (int idx = tid; idx < 32 * H_; idx += 256) {
        int bb = idx / H_, h = idx % H_;
        float s = 0.f;
        #pragma unroll
        for (int k = 0; k < K_; ++k) {
            int tau = t - (K_ - 1) + k;
            if (tau >= 0)
                s += ldl[bb][k] * bf2f(hbf[((size_t)tau * B_ + b0 + bb) * H_ + h]);
        }
        hbar[bb][h] = s * (1.f / K_);
    }
    __syncthreads();

    for (int idx = tid; idx < 32 * HS_; idx += 256) {
        int bb = idx >> 6, jj = idx & 63;
        float s = bs[jj];
        for (int h = 0; h < H_; ++h) s = fmaf(hbar[bb][h], Ws[h * HS_ + jj], s);
        us[bb][jj] = fmaxf(s, 0.f);
    }
    __syncthreads();

    for (int idx = tid; idx < 32 * H_; idx += 256) {
        int bb = idx / H_, o = idx % H_;
        float s = brs[o];
        #pragma unroll
        for (int jj = 0; jj < HS_; ++jj) s = fmaf(us[bb][jj], Wrs[jj * H_ + o], s);
        float th = sigf(s);
        size_t gi = ((size_t)(b0 + bb) * T_ + t) * H_ + o;
        out_part[gi] = bf2f(hbf[((size_t)t * B_ + b0 + bb) * H_ + o])
                     + th * (out_part[gi] + bc[o]);
    }
}

// ---------------- last_output gather ----------------
__global__ void k_last(const int* __restrict__ len_i, const float* __restrict__ out_part,
                       float* __restrict__ last)
{
    int b = blockIdx.x, tid = threadIdx.x;
    bool is64 = (len_i[1] == 0);
    long long v = is64 ? ((const long long*)len_i)[b] : (long long)len_i[b];
    int idx = (int)v;
    idx = max(1, min(T_, idx)) - 1;
    last[(size_t)b * H_ + tid] = out_part[((size_t)b * T_ + idx) * H_ + tid];
}

extern "C" void kernel_launch(void* const* d_in, const int* in_sizes, int n_in,
                              void* d_out, int out_size, void* d_ws, size_t ws_size,
                              hipStream_t stream) {
    const float* x   = (const float*)d_in[0];
    const int*   len = (const int*)d_in[1];
    const float* Wk  = (const float*)d_in[2];
    const float* bk  = (const float*)d_in[3];
    const float* Wr  = (const float*)d_in[4];
    const float* br  = (const float*)d_in[5];
    const float* Ws  = (const float*)d_in[6];
    const float* bs  = (const float*)d_in[7];
    const float* Wrs = (const float*)d_in[8];
    const float* brs = (const float*)d_in[9];
    const float* Wc  = (const float*)d_in[10];
    const float* bc  = (const float*)d_in[11];

    float* out      = (float*)d_out;
    float* last     = out;
    float* out_part = out + (size_t)B_ * H_;

    // workspace layout (float slots); total ~24.11M floats (~96.4 MB)
    float* w = (float*)d_ws;
    float*          cT    = w;                                   // 98304
    float*          hT    = cT + 98304;                          // 196608 (2x384x256)
    int*            bar   = (int*)(hT + 196608);                 // 256 slots
    float*          xoT   = (float*)bar + 256;                   // 394752 (G x B)
    float*          dis   = xoT + (size_t)G_ * B_;               // 65536
    float*          ld    = dis + (size_t)T_ * B_;               // 655360
    float*          Wser  = ld + (size_t)T_ * B_ * K_;           // 986880
    float*          biasv = Wser + (size_t)G_ * 640;             // 2048
    unsigned short* xT    = (unsigned short*)(biasv + 2048);     // 16777216 bf16
    unsigned short* hbf   = xT + (size_t)T_ * D_ * B_;           // 25165824 bf16
    unsigned short* Wg    = hbf + (size_t)T_ * B_ * H_;          // 1474560 bf16

    const int nzero = 98304 + 196608 + 256;
    k_zero<<<(nzero + 255) / 256, 256, 0, stream>>>(cT, nzero);
    k_xt  <<<dim3(T_, 4, 4), 256, 0, stream>>>(x, xT);
    k_pack<<<(G_ * 640 + G_ + 255) / 256, 256, 0, stream>>>(Wk, bk, Wr, br, Wser, biasv);
    k_wg  <<<(H_ * K_ * H_ + 255) / 256, 256, 0, stream>>>(Wc, Wg);

    k_serial<<<NBS, 256, 0, stream>>>(xT, Wser, biasv, hT, cT, xoT, hbf, dis, bar);

    k_ld   <<<T_, B_, 0, stream>>>(dis, ld);
    k_conv <<<dim3(4, T_), 256, 0, stream>>>(hbf, ld, Wg, out_part);
    k_theme<<<dim3(8, T_), 256, 0, stream>>>(hbf, ld, Ws, bs, Wrs, brs, bc, out_part);
    k_last <<<B_, H_, 0, stream>>>(len, out_part, last);
}

// Round 3
// 6666.340 us; speedup vs baseline: 6.1633x; 6.1633x over previous
//
#include <hip/hip_runtime.h>
#include <hip/hip_bf16.h>
#include <cstddef>

// Problem constants
#define B_  256
#define T_  256
#define D_  256
#define H_  384
#define G_  1542
#define L_  3
#define CH_ 128
#define K_  10
#define HS_ 64

// Serial-phase geometry: 8 groups (32 b each) x 16 members (24 ch, 102 cols -> 7 frags)
#define NGRP 8
#define NMEM 16
#define CPM  24          // channels per member
#define NFR  7           // N-frags (112 packed cols: 6 cumax + 96 gates + 10 pad)
#define PCOLS 112
#define XOLP 114         // xol row stride (floats), padded vs 112 for bank spread
#define NKC  20          // k-chunks of 32 (inner 640 = 256 x + 384 h)
// LDS layout (bytes)
#define W_LDS   (NKC * NFR * 64 * 8 * 2)     // 143360
#define BIAS_OFF W_LDS                        // 112 floats (pad 512)
#define UNI_OFF (W_LDS + 512)                 // union: hAf (6*2*64*16=12288) / xol (32*114*4=14592)
#define LDS_BYTES (UNI_OFF + 32 * XOLP * 4)   // 158464

using bf16x8 = __attribute__((ext_vector_type(8))) short;
using f32x4  = __attribute__((ext_vector_type(4))) float;

__device__ __forceinline__ float sigf(float x) { return 1.f / (1.f + expf(-x)); }
__device__ __forceinline__ float bf2f(unsigned short s) {
    return __uint_as_float(((unsigned)s) << 16);
}
__device__ __forceinline__ unsigned short f2bf(float f) {
    unsigned u = __float_as_uint(f);
    return (unsigned short)((u + 0x7fffu + ((u >> 16) & 1u)) >> 16);
}

// ---------------- zero ----------------
__global__ void k_zero(float* __restrict__ p, int n) {
    int i = blockIdx.x * blockDim.x + threadIdx.x;
    if (i < n) p[i] = 0.f;
}

// ---------------- xA: A-frag-ordered x (bf16) ----------------
// xA[t][kc0..7][group][mi][lane][j] = x[b][t][d], b=group*32+mi*16+(lane&15),
// d = kc*32+(lane>>4)*8+j
__global__ __launch_bounds__(256)
void k_xa(const float* __restrict__ x, unsigned short* __restrict__ xA) {
    int gtid = blockIdx.x * 256 + threadIdx.x;       // < 2^21
    int lane = gtid & 63;
    int mi   = (gtid >> 6) & 1;
    int group= (gtid >> 7) & 7;
    int kc   = (gtid >> 10) & 7;
    int t    = gtid >> 13;
    int b = group * 32 + mi * 16 + (lane & 15);
    int d = kc * 32 + (lane >> 4) * 8;
    const float* src = x + ((size_t)b * T_ + t) * D_ + d;
    float4 v0 = *(const float4*)src;
    float4 v1 = *(const float4*)(src + 4);
    int4 pk;
    pk.x = (unsigned)f2bf(v0.x) | ((unsigned)f2bf(v0.y) << 16);
    pk.y = (unsigned)f2bf(v0.z) | ((unsigned)f2bf(v0.w) << 16);
    pk.z = (unsigned)f2bf(v1.x) | ((unsigned)f2bf(v1.y) << 16);
    pk.w = (unsigned)f2bf(v1.z) | ((unsigned)f2bf(v1.w) << 16);
    ((int4*)xA)[gtid] = pk;
}

// packed col -> gate col (or -1 for pad)
__device__ __forceinline__ int gcol_of(int member, int p) {
    if (p < 6) return p;
    if (p < 102) { int q = p - 6; return 6 + (q / CPM) * H_ + member * CPM + (q % CPM); }
    return -1;
}

// ---------------- Wfrag: B-frag-ordered serial weights (bf16) ----------------
// Wf[member][kc][ni][lane][j] = W[k][gcol], k = kc*32+(lane>>4)*8+j
__global__ __launch_bounds__(256)
void k_wfrag(const float* __restrict__ Wk, const float* __restrict__ Wr,
             unsigned short* __restrict__ Wf) {
    int idx = blockIdx.x * 256 + threadIdx.x;        // < 16*20*7*64 = 143360
    if (idx >= NMEM * NKC * NFR * 64) return;
    int lane = idx & 63;
    int ni   = (idx >> 6) % NFR;
    int kc   = (idx / (64 * NFR)) % NKC;
    int member = idx / (64 * NFR * NKC);
    int p = ni * 16 + (lane & 15);
    int g = gcol_of(member, p);
    unsigned short out[8];
    #pragma unroll
    for (int j = 0; j < 8; ++j) {
        int k = kc * 32 + (lane >> 4) * 8 + j;
        float v = 0.f;
        if (g >= 0) v = (k < 256) ? Wk[(size_t)k * G_ + g] : Wr[(size_t)(k - 256) * G_ + g];
        out[j] = f2bf(v);
    }
    int4 pk;
    pk.x = (unsigned)out[0] | ((unsigned)out[1] << 16);
    pk.y = (unsigned)out[2] | ((unsigned)out[3] << 16);
    pk.z = (unsigned)out[4] | ((unsigned)out[5] << 16);
    pk.w = (unsigned)out[6] | ((unsigned)out[7] << 16);
    ((int4*)Wf)[idx] = pk;
}

// ---------------- biasP[member][p] ----------------
__global__ void k_bias(const float* __restrict__ Wk, const float* __restrict__ bk,
                       const float* __restrict__ Wr, const float* __restrict__ br,
                       float* __restrict__ biasP) {
    int idx = blockIdx.x * 256 + threadIdx.x;
    if (idx >= NMEM * PCOLS) return;
    int member = idx / PCOLS, p = idx % PCOLS;
    int g = gcol_of(member, p);
    biasP[idx] = (g >= 0)
        ? bk[g] + br[g] + Wk[(size_t)256 * G_ + g] + Wr[(size_t)384 * G_ + g] : 0.f;
}

// ---------------- conv weights: Wg[o][k*384+h] (bf16) ----------------
__global__ void k_wg(const float* __restrict__ Wc, unsigned short* __restrict__ Wg) {
    int idx = blockIdx.x * 256 + threadIdx.x;
    if (idx >= H_ * K_ * H_) return;
    int o = idx / (K_ * H_);
    int rem = idx % (K_ * H_);
    int k = rem / H_, h = rem % H_;
    Wg[idx] = f2bf(Wc[((size_t)o * H_ + h) * K_ + k]);
}

// ---------------- persistent serial recurrence ----------------
__global__ __launch_bounds__(256, 1)
void k_serial(const unsigned short* __restrict__ xA, const unsigned short* __restrict__ Wf,
              const float* __restrict__ biasP, float* __restrict__ hser,
              unsigned short* __restrict__ hbf, float* __restrict__ dis,
              unsigned* __restrict__ bar)
{
    extern __shared__ char lds_raw[];
    unsigned short* Wl = (unsigned short*)lds_raw;
    float* biasL = (float*)(lds_raw + BIAS_OFF);
    char* uni = lds_raw + UNI_OFF;
    float* xol = (float*)uni;

    const int tid = threadIdx.x;
    const int lane = tid & 63, wave = tid >> 6;
    const int group = blockIdx.x & 7, member = blockIdx.x >> 3;
    const int b0 = group * 32;
    const int ni0 = wave, ni1 = wave + 4;
    const bool has1 = (ni1 < NFR);

    // one-time: weights + bias into LDS
    {
        const int4* src = (const int4*)(Wf + (size_t)member * (NKC * NFR * 64 * 8));
        for (int i = tid; i < W_LDS / 16; i += 256) ((int4*)Wl)[i] = src[i];
        if (tid < PCOLS) biasL[tid] = biasP[member * PCOLS + tid];
    }
    __syncthreads();

    const float bias_a = biasL[ni0 * 16 + (lane & 15)];
    const float bias_b = has1 ? biasL[ni1 * 16 + (lane & 15)] : 0.f;

    float c_r[3] = {0.f, 0.f, 0.f};
    unsigned* mybar = bar + group * 32;

    for (int t = 0; t < T_; ++t) {
        // prefetch x A-frags (independent of barrier)
        bf16x8 xf[8][2];
        #pragma unroll
        for (int kc = 0; kc < 8; ++kc)
            #pragma unroll
            for (int mi = 0; mi < 2; ++mi)
                xf[kc][mi] = *((const bf16x8*)(xA
                    + ((((size_t)t * 8 + kc) * 8 + group) * 2 + mi) * 512 + lane * 8));

        // ---- stage h half1 (k-chunks 8..13) ----
        if (t > 0) {
            const int par = (t - 1) & 1;
            #pragma unroll
            for (int i = 0; i < 3; ++i) {
                int s = tid + 256 * i;               // < 768
                int kch = s >> 7, mi = (s >> 6) & 1, ln = s & 63;
                int b = b0 + mi * 16 + (ln & 15);
                int h0i = kch * 32 + (ln >> 4) * 8;
                const unsigned long long* src =
                    (const unsigned long long*)(hser + (size_t)par * (B_ * H_) + (size_t)b * H_ + h0i);
                int4 pk;
                unsigned* pku = (unsigned*)&pk;
                #pragma unroll
                for (int q = 0; q < 4; ++q) {
                    unsigned long long d = __hip_atomic_load(src + q, __ATOMIC_RELAXED,
                                                             __HIP_MEMORY_SCOPE_AGENT);
                    float lo = __uint_as_float((unsigned)(d & 0xffffffffu));
                    float hi = __uint_as_float((unsigned)(d >> 32));
                    pku[q] = (unsigned)f2bf(lo) | ((unsigned)f2bf(hi) << 16);
                }
                ((int4*)uni)[(kch * 2 + mi) * 64 + ln] = pk;
            }
        }
        __syncthreads();

        // ---- MFMA phase 1: kc 0..13 ----
        f32x4 acc[2][2];
        #pragma unroll
        for (int mi = 0; mi < 2; ++mi) {
            acc[mi][0] = f32x4{bias_a, bias_a, bias_a, bias_a};
            acc[mi][1] = f32x4{bias_b, bias_b, bias_b, bias_b};
        }
        const int kcend1 = (t == 0) ? 8 : 14;
        for (int kc = 0; kc < kcend1; ++kc) {
            bf16x8 a0, a1;
            if (kc < 8) { a0 = xf[kc][0]; a1 = xf[kc][1]; }
            else {
                a0 = ((const bf16x8*)uni)[((kc - 8) * 2 + 0) * 64 + lane];
                a1 = ((const bf16x8*)uni)[((kc - 8) * 2 + 1) * 64 + lane];
            }
            bf16x8 w0 = ((const bf16x8*)Wl)[(kc * NFR + ni0) * 64 + lane];
            acc[0][0] = __builtin_amdgcn_mfma_f32_16x16x32_bf16(a0, w0, acc[0][0], 0, 0, 0);
            acc[1][0] = __builtin_amdgcn_mfma_f32_16x16x32_bf16(a1, w0, acc[1][0], 0, 0, 0);
            if (has1) {
                bf16x8 w1 = ((const bf16x8*)Wl)[(kc * NFR + ni1) * 64 + lane];
                acc[0][1] = __builtin_amdgcn_mfma_f32_16x16x32_bf16(a0, w1, acc[0][1], 0, 0, 0);
                acc[1][1] = __builtin_amdgcn_mfma_f32_16x16x32_bf16(a1, w1, acc[1][1], 0, 0, 0);
            }
        }

        if (t > 0) {
            __syncthreads();
            // ---- stage h half2 (k-chunks 14..19) ----
            const int par = (t - 1) & 1;
            #pragma unroll
            for (int i = 0; i < 3; ++i) {
                int s = tid + 256 * i;
                int kch = s >> 7, mi = (s >> 6) & 1, ln = s & 63;
                int b = b0 + mi * 16 + (ln & 15);
                int h0i = (6 + kch) * 32 + (ln >> 4) * 8;
                const unsigned long long* src =
                    (const unsigned long long*)(hser + (size_t)par * (B_ * H_) + (size_t)b * H_ + h0i);
                int4 pk;
                unsigned* pku = (unsigned*)&pk;
                #pragma unroll
                for (int q = 0; q < 4; ++q) {
                    unsigned long long d = __hip_atomic_load(src + q, __ATOMIC_RELAXED,
                                                             __HIP_MEMORY_SCOPE_AGENT);
                    float lo = __uint_as_float((unsigned)(d & 0xffffffffu));
                    float hi = __uint_as_float((unsigned)(d >> 32));
                    pku[q] = (unsigned)f2bf(lo) | ((unsigned)f2bf(hi) << 16);
                }
                ((int4*)uni)[(kch * 2 + mi) * 64 + ln] = pk;
            }
            __syncthreads();
            // ---- MFMA phase 2: kc 14..19 ----
            for (int kc = 14; kc < 20; ++kc) {
                bf16x8 a0 = ((const bf16x8*)uni)[((kc - 14) * 2 + 0) * 64 + lane];
                bf16x8 a1 = ((const bf16x8*)uni)[((kc - 14) * 2 + 1) * 64 + lane];
                bf16x8 w0 = ((const bf16x8*)Wl)[(kc * NFR + ni0) * 64 + lane];
                acc[0][0] = __builtin_amdgcn_mfma_f32_16x16x32_bf16(a0, w0, acc[0][0], 0, 0, 0);
                acc[1][0] = __builtin_amdgcn_mfma_f32_16x16x32_bf16(a1, w0, acc[1][0], 0, 0, 0);
                if (has1) {
                    bf16x8 w1 = ((const bf16x8*)Wl)[(kc * NFR + ni1) * 64 + lane];
                    acc[0][1] = __builtin_amdgcn_mfma_f32_16x16x32_bf16(a0, w1, acc[0][1], 0, 0, 0);
                    acc[1][1] = __builtin_amdgcn_mfma_f32_16x16x32_bf16(a1, w1, acc[1][1], 0, 0, 0);
                }
            }
        }
        __syncthreads();   // hAf dead; xol reuses the region

        // ---- write xo slice to LDS ----
        #pragma unroll
        for (int mi = 0; mi < 2; ++mi) {
            int brow = mi * 16 + ((lane >> 4) << 2);
            #pragma unroll
            for (int r = 0; r < 4; ++r)
                xol[(brow + r) * XOLP + ni0 * 16 + (lane & 15)] = acc[mi][0][r];
            if (has1)
                #pragma unroll
                for (int r = 0; r < 4; ++r)
                    xol[(brow + r) * XOLP + ni1 * 16 + (lane & 15)] = acc[mi][1][r];
        }
        __syncthreads();

        // ---- gates ----
        #pragma unroll
        for (int r = 0; r < 3; ++r) {
            int item = tid + 256 * r;                // < 768
            int b = item & 31, ch = item >> 5;
            const float* row = xol + b * XOLP;
            float z0 = row[0], z1 = row[1], z2 = row[2];
            float z3 = row[3], z4 = row[4], z5 = row[5];
            float m1 = fmaxf(fmaxf(z0, z1), z2);
            float e0 = expf(z0 - m1), e1 = expf(z1 - m1), e2 = expf(z2 - m1);
            float s1 = e0 + e1 + e2;
            float fm0 = e0 / s1, fm1 = (e0 + e1) / s1;
            float m2 = fmaxf(fmaxf(z3, z4), z5);
            float f3 = expf(z3 - m2), f4 = expf(z4 - m2), f5 = expf(z5 - m2);
            float s2 = f3 + f4 + f5;
            float im1 = (f4 + f5) / s2, im2 = f5 / s2;

            int hh = member * CPM + ch;
            int l = hh >> 7;
            float fm = (l == 0) ? fm0 : (l == 1) ? fm1 : 1.f;
            float im = (l == 0) ? 1.f : (l == 1) ? im1 : im2;

            float fg = sigf(row[6 + ch]);
            float ig = sigf(row[6 + CPM + ch]);
            float og = sigf(row[6 + 2 * CPM + ch]);
            float ci = tanhf(row[6 + 3 * CPM + ch]);

            float cl = c_r[r];
            float ov = fm * im;
            float cn = ov * (fg * cl + ig * ci) + (fm - ov) * cl + (im - ov) * ci;
            float hn = og * tanhf(cn);
            c_r[r] = cn;

            int gb = b0 + b;
            __hip_atomic_store(hser + (size_t)(t & 1) * (B_ * H_) + (size_t)gb * H_ + hh,
                               hn, __ATOMIC_RELAXED, __HIP_MEMORY_SCOPE_AGENT);
            hbf[((size_t)t * B_ + gb) * H_ + hh] = f2bf(hn);
            if (member == 0 && ch == 0)
                dis[t * B_ + gb] = 1.f - (fm0 + fm1 + 1.f) * (1.f / 3.f);
        }
        __syncthreads();   // drain all waves' h stores (vmcnt(0) per wave)

        // ---- per-group barrier ----
        if (tid == 0) {
            __hip_atomic_fetch_add(mybar, 1u, __ATOMIC_RELEASE, __HIP_MEMORY_SCOPE_AGENT);
            unsigned tgt = (unsigned)(NMEM * (t + 1));
            while (__hip_atomic_load(mybar, __ATOMIC_RELAXED, __HIP_MEMORY_SCOPE_AGENT) < tgt)
                __builtin_amdgcn_s_sleep(2);
        }
        __syncthreads();
    }
}

// ---------------- ld weights ----------------
__global__ void k_ld(const float* __restrict__ dis_all, float* __restrict__ ld_all)
{
    int t = blockIdx.x, b = threadIdx.x;
    float s = 0.f, sk[K_];
    #pragma unroll
    for (int k = 0; k < K_; ++k) {
        int tau = t - (K_ - 1) + k;
        float d = (tau >= 0) ? dis_all[tau * B_ + b] : 0.f;
        s += d; sk[k] = s;
    }
    float m = sk[0];
    #pragma unroll
    for (int k = 1; k < K_; ++k) m = fmaxf(m, sk[k]);
    float sum = 0.f;
    #pragma unroll
    for (int k = 0; k < K_; ++k) { sk[k] = expf(sk[k] - m); sum += sk[k]; }
    float inv = 1.f / sum;
    #pragma unroll
    for (int k = 0; k < K_; ++k)
        ld_all[((size_t)t * B_ + b) * K_ + k] = sk[k] * inv;
}

// ---------------- conv via MFMA ----------------
__global__ __launch_bounds__(256)
void k_conv(const unsigned short* __restrict__ hbf, const float* __restrict__ ld_all,
            const unsigned short* __restrict__ Wg, float* __restrict__ out_part)
{
    __shared__ unsigned short Al[64][40];
    __shared__ unsigned short Bl[384][40];
    __shared__ float ldl[64][10];
    const int b0 = blockIdx.x * 64;
    const int t  = blockIdx.y;
    const int tid = threadIdx.x;
    const int wave = tid >> 6, lane = tid & 63;

    for (int idx = tid; idx < 64 * K_; idx += 256)
        ldl[idx / K_][idx % K_] = ld_all[((size_t)t * B_ + b0 + idx / K_) * K_ + idx % K_];
    __syncthreads();

    f32x4 acc[4][6] = {};
    const int arow = tid & 63, ahalf = tid >> 6;

    for (int ch = 0; ch < 120; ++ch) {
        int k = ch / 12, h0 = (ch % 12) * 32;
        int tau = t - (K_ - 1) + k;
        {
            int4 pk;
            if (tau >= 0) {
                float l = ldl[arow][k];
                const unsigned short* hp =
                    hbf + ((size_t)tau * B_ + b0 + arow) * H_ + h0 + ahalf * 8;
                int4 v = *(const int4*)hp;
                unsigned vv[4] = {(unsigned)v.x, (unsigned)v.y, (unsigned)v.z, (unsigned)v.w};
                unsigned out[4];
                #pragma unroll
                for (int q = 0; q < 4; ++q) {
                    float flo = __uint_as_float(vv[q] << 16) * l;
                    float fhi = __uint_as_float(vv[q] & 0xffff0000u) * l;
                    out[q] = (unsigned)f2bf(flo) | ((unsigned)f2bf(fhi) << 16);
                }
                pk = make_int4((int)out[0], (int)out[1], (int)out[2], (int)out[3]);
            } else {
                pk = make_int4(0, 0, 0, 0);
            }
            *(int4*)&Al[arow][ahalf * 8] = pk;
        }
        #pragma unroll
        for (int q = 0; q < 6; ++q) {
            int idx = q * 256 + tid;
            int row = idx >> 2, half = idx & 3;
            const unsigned short* wp = Wg + (size_t)row * 3840 + ch * 32 + half * 8;
            *(int4*)&Bl[row][half * 8] = *(const int4*)wp;
        }
        __syncthreads();

        bf16x8 af[4];
        #pragma unroll
        for (int mi = 0; mi < 4; ++mi)
            af[mi] = *(const bf16x8*)&Al[mi * 16 + (lane & 15)][(lane >> 4) * 8];
        #pragma unroll
        for (int ni = 0; ni < 6; ++ni) {
            bf16x8 bfv = *(const bf16x8*)&Bl[wave * 96 + ni * 16 + (lane & 15)][(lane >> 4) * 8];
            #pragma unroll
            for (int mi = 0; mi < 4; ++mi)
                acc[mi][ni] = __builtin_amdgcn_mfma_f32_16x16x32_bf16(af[mi], bfv, acc[mi][ni], 0, 0, 0);
        }
        __syncthreads();
    }
    #pragma unroll
    for (int mi = 0; mi < 4; ++mi) {
        #pragma unroll
        for (int ni = 0; ni < 6; ++ni) {
            int o = wave * 96 + ni * 16 + (lane & 15);
            int brow = b0 + mi * 16 + ((lane >> 4) << 2);
            #pragma unroll
            for (int r = 0; r < 4; ++r)
                out_part[((size_t)(brow + r) * T_ + t) * H_ + o] = acc[mi][ni][r];
        }
    }
}

// ---------------- theme + combine ----------------
__global__ __launch_bounds__(256)
void k_theme(const unsigned short* __restrict__ hbf, const float* __restrict__ ld_all,
             const float* __restrict__ Ws, const float* __restrict__ bs,
             const float* __restrict__ Wrs, const float* __restrict__ brs,
             const float* __restrict__ bc, float* __restrict__ out_part)
{
    __shared__ float hbar[32][385];
    __shared__ float us[32][65];
    __shared__ float ldl[32][10];
    const int b0 = blockIdx.x * 32, t = blockIdx.y, tid = threadIdx.x;

    for (int idx = tid; idx < 32 * K_; idx += 256)
        ldl[idx / K_][idx % K_] = ld_all[((size_t)t * B_ + b0 + idx / K_) * K_ + idx % K_];
    __syncthreads();

    for (int idx = tid; idx < 32 * H_; idx += 256) {
        int bb = idx / H_, h = idx % H_;
        float s = 0.f;
        #pragma unroll
        for (int k = 0; k < K_; ++k) {
            int tau = t - (K_ - 1) + k;
            if (tau >= 0)
                s += ldl[bb][k] * bf2f(hbf[((size_t)tau * B_ + b0 + bb) * H_ + h]);
        }
        hbar[bb][h] = s * (1.f / K_);
    }
    __syncthreads();

    for (int idx = tid; idx < 32 * HS_; idx += 256) {
        int bb = idx >> 6, jj = idx & 63;
        float s = bs[jj];
        for (int h = 0; h < H_; ++h) s = fmaf(hbar[bb][h], Ws[h * HS_ + jj], s);
        us[bb][jj] = fmaxf(s, 0.f);
    }
    __syncthreads();

    for (int idx = tid; idx < 32 * H_; idx += 256) {
        int bb = idx / H_, o = idx % H_;
        float s = brs[o];
        #pragma unroll
        for (int jj = 0; jj < HS_; ++jj) s = fmaf(us[bb][jj], Wrs[jj * H_ + o], s);
        float th = sigf(s);
        size_t gi = ((size_t)(b0 + bb) * T_ + t) * H_ + o;
        out_part[gi] = bf2f(hbf[((size_t)t * B_ + b0 + bb) * H_ + o])
                     + th * (out_part[gi] + bc[o]);
    }
}

// ---------------- last_output gather ----------------
__global__ void k_last(const int* __restrict__ len_i, const float* __restrict__ out_part,
                       float* __restrict__ last)
{
    int b = blockIdx.x, tid = threadIdx.x;
    bool is64 = (len_i[1] == 0);
    long long v = is64 ? ((const long long*)len_i)[b] : (long long)len_i[b];
    int idx = (int)v;
    idx = max(1, min(T_, idx)) - 1;
    last[(size_t)b * H_ + tid] = out_part[((size_t)b * T_ + idx) * H_ + tid];
}

extern "C" void kernel_launch(void* const* d_in, const int* in_sizes, int n_in,
                              void* d_out, int out_size, void* d_ws, size_t ws_size,
                              hipStream_t stream) {
    const float* x   = (const float*)d_in[0];
    const int*   len = (const int*)d_in[1];
    const float* Wk  = (const float*)d_in[2];
    const float* bk  = (const float*)d_in[3];
    const float* Wr  = (const float*)d_in[4];
    const float* br  = (const float*)d_in[5];
    const float* Ws  = (const float*)d_in[6];
    const float* bs  = (const float*)d_in[7];
    const float* Wrs = (const float*)d_in[8];
    const float* brs = (const float*)d_in[9];
    const float* Wc  = (const float*)d_in[10];
    const float* bc  = (const float*)d_in[11];

    float* out      = (float*)d_out;
    float* last     = out;
    float* out_part = out + (size_t)B_ * H_;

    // workspace layout (bytes), total ~92.8 MB
    char* p = (char*)d_ws;
    unsigned*       bar    = (unsigned*)p;       p += 1024;
    float*          hser   = (float*)p;          p += (size_t)2 * B_ * H_ * 4;      // 786432
    float*          dis    = (float*)p;          p += (size_t)T_ * B_ * 4;          // 262144
    float*          ld     = (float*)p;          p += (size_t)T_ * B_ * K_ * 4;     // 2621440
    unsigned short* xA     = (unsigned short*)p; p += (size_t)T_ * B_ * D_ * 2;     // 33554432
    unsigned short* WfragG = (unsigned short*)p; p += (size_t)NMEM * NKC * NFR * 64 * 8 * 2; // 2293760
    float*          biasP  = (float*)p;          p += (size_t)NMEM * PCOLS * 4;     // 7168
    unsigned short* hbf    = (unsigned short*)p; p += (size_t)T_ * B_ * H_ * 2;     // 50331648
    unsigned short* Wg     = (unsigned short*)p; p += (size_t)H_ * K_ * H_ * 2;     // 2949120

    k_zero <<<1, 256, 0, stream>>>((float*)bar, 256);
    k_xa   <<<8192, 256, 0, stream>>>(x, xA);
    k_wfrag<<<(NMEM * NKC * NFR * 64 + 255) / 256, 256, 0, stream>>>(Wk, Wr, WfragG);
    k_bias <<<(NMEM * PCOLS + 255) / 256, 256, 0, stream>>>(Wk, bk, Wr, br, biasP);
    k_wg   <<<(H_ * K_ * H_ + 255) / 256, 256, 0, stream>>>(Wc, Wg);

    hipFuncSetAttribute((const void*)k_serial,
                        hipFuncAttributeMaxDynamicSharedMemorySize, LDS_BYTES);
    k_serial<<<NGRP * NMEM, 256, LDS_BYTES, stream>>>(xA, WfragG, biasP, hser, hbf, dis, bar);

    k_ld   <<<T_, B_, 0, stream>>>(dis, ld);
    k_conv <<<dim3(4, T_), 256, 0, stream>>>(hbf, ld, Wg, out_part);
    k_theme<<<dim3(8, T_), 256, 0, stream>>>(hbf, ld, Ws, bs, Wrs, brs, bc, out_part);
    k_last <<<B_, H_, 0, stream>>>(len, out_part, last);
}

// Round 4
// 2926.050 us; speedup vs baseline: 14.0416x; 2.2783x over previous
//
#include <hip/hip_runtime.h>
#include <hip/hip_bf16.h>
#include <cstddef>

// Problem constants
#define B_  256
#define T_  256
#define D_  256
#define H_  384
#define G_  1542
#define L_  3
#define CH_ 128
#define K_  10
#define HS_ 64

// Serial-phase geometry: 8 groups (32 b each) x 16 members (24 ch, 102 cols -> 7 frags)
#define NGRP 8
#define NMEM 16
#define CPM  24          // channels per member
#define NFR  7           // N-frags (112 packed cols: 6 cumax + 96 gates + 10 pad)
#define PCOLS 112
#define XOLP 114         // xol row stride (floats)
#define NKC  20          // inner k-chunks of 32 (640 = 256 x + 384 h)
// LDS layout (bytes)
#define W_LDS    (NKC * NFR * 64 * 8 * 2)   // 143360
#define BIAS_OFF W_LDS                       // 112 floats (pad to 512)
#define UNI_OFF  (W_LDS + 512)               // union: stage (6kc*2mi*64*16=12288) / xol+hout
#define HOUT_OFF 14592                       // within union: after xol (32*114*4)
#define LDS_BYTES (UNI_OFF + HOUT_OFF + 32 * CPM * 2)   // 160000

using bf16x8 = __attribute__((ext_vector_type(8))) short;
using f32x4  = __attribute__((ext_vector_type(4))) float;

__device__ __forceinline__ float sigf(float x) { return 1.f / (1.f + expf(-x)); }
__device__ __forceinline__ float bf2f(unsigned short s) {
    return __uint_as_float(((unsigned)s) << 16);
}
__device__ __forceinline__ unsigned short f2bf(float f) {
    unsigned u = __float_as_uint(f);
    return (unsigned short)((u + 0x7fffu + ((u >> 16) & 1u)) >> 16);
}

// ---------------- zero ----------------
__global__ void k_zero(float* __restrict__ p, int n) {
    int i = blockIdx.x * blockDim.x + threadIdx.x;
    if (i < n) p[i] = 0.f;
}

// ---------------- xA: A-frag-ordered x (bf16) ----------------
__global__ __launch_bounds__(256)
void k_xa(const float* __restrict__ x, unsigned short* __restrict__ xA) {
    int gtid = blockIdx.x * 256 + threadIdx.x;       // < 2^21
    int lane = gtid & 63;
    int mi   = (gtid >> 6) & 1;
    int group= (gtid >> 7) & 7;
    int kc   = (gtid >> 10) & 7;
    int t    = gtid >> 13;
    int b = group * 32 + mi * 16 + (lane & 15);
    int d = kc * 32 + (lane >> 4) * 8;
    const float* src = x + ((size_t)b * T_ + t) * D_ + d;
    float4 v0 = *(const float4*)src;
    float4 v1 = *(const float4*)(src + 4);
    int4 pk;
    pk.x = (unsigned)f2bf(v0.x) | ((unsigned)f2bf(v0.y) << 16);
    pk.y = (unsigned)f2bf(v0.z) | ((unsigned)f2bf(v0.w) << 16);
    pk.z = (unsigned)f2bf(v1.x) | ((unsigned)f2bf(v1.y) << 16);
    pk.w = (unsigned)f2bf(v1.z) | ((unsigned)f2bf(v1.w) << 16);
    ((int4*)xA)[gtid] = pk;
}

// packed col -> gate col (or -1 for pad)
__device__ __forceinline__ int gcol_of(int member, int p) {
    if (p < 6) return p;
    if (p < 102) { int q = p - 6; return 6 + (q / CPM) * H_ + member * CPM + (q % CPM); }
    return -1;
}

// ---------------- Wfrag: B-frag-ordered serial weights (bf16) ----------------
__global__ __launch_bounds__(256)
void k_wfrag(const float* __restrict__ Wk, const float* __restrict__ Wr,
             unsigned short* __restrict__ Wf) {
    int idx = blockIdx.x * 256 + threadIdx.x;        // < 16*20*7*64 = 143360
    if (idx >= NMEM * NKC * NFR * 64) return;
    int lane = idx & 63;
    int ni   = (idx >> 6) % NFR;
    int kc   = (idx / (64 * NFR)) % NKC;
    int member = idx / (64 * NFR * NKC);
    int p = ni * 16 + (lane & 15);
    int g = gcol_of(member, p);
    unsigned short out[8];
    #pragma unroll
    for (int j = 0; j < 8; ++j) {
        int k = kc * 32 + (lane >> 4) * 8 + j;
        float v = 0.f;
        if (g >= 0) v = (k < 256) ? Wk[(size_t)k * G_ + g] : Wr[(size_t)(k - 256) * G_ + g];
        out[j] = f2bf(v);
    }
    int4 pk;
    pk.x = (unsigned)out[0] | ((unsigned)out[1] << 16);
    pk.y = (unsigned)out[2] | ((unsigned)out[3] << 16);
    pk.z = (unsigned)out[4] | ((unsigned)out[5] << 16);
    pk.w = (unsigned)out[6] | ((unsigned)out[7] << 16);
    ((int4*)Wf)[idx] = pk;
}

// ---------------- biasP[member][p] ----------------
__global__ void k_bias(const float* __restrict__ Wk, const float* __restrict__ bk,
                       const float* __restrict__ Wr, const float* __restrict__ br,
                       float* __restrict__ biasP) {
    int idx = blockIdx.x * 256 + threadIdx.x;
    if (idx >= NMEM * PCOLS) return;
    int member = idx / PCOLS, p = idx % PCOLS;
    int g = gcol_of(member, p);
    biasP[idx] = (g >= 0)
        ? bk[g] + br[g] + Wk[(size_t)256 * G_ + g] + Wr[(size_t)384 * G_ + g] : 0.f;
}

// ---------------- conv weights: Wg[o][k*384+h] (bf16) ----------------
__global__ void k_wg(const float* __restrict__ Wc, unsigned short* __restrict__ Wg) {
    int idx = blockIdx.x * 256 + threadIdx.x;
    if (idx >= H_ * K_ * H_) return;
    int o = idx / (K_ * H_);
    int rem = idx % (K_ * H_);
    int k = rem / H_, h = rem % H_;
    Wg[idx] = f2bf(Wc[((size_t)o * H_ + h) * K_ + k]);
}

// ---------------- persistent serial recurrence ----------------
// h exchange: bf16 via hbf with RELAXED agent atomics only (no RMW, no release,
// no wbl2). Barrier: per-member flag array, relaxed stores + parallel polls.
__global__ __launch_bounds__(256, 1)
void k_serial(const unsigned short* __restrict__ xA, const unsigned short* __restrict__ Wf,
              const float* __restrict__ biasP,
              unsigned short* __restrict__ hbf, float* __restrict__ dis,
              unsigned* __restrict__ flags)
{
    extern __shared__ char lds_raw[];
    unsigned short* Wl = (unsigned short*)lds_raw;
    float* biasL = (float*)(lds_raw + BIAS_OFF);
    char* uni = lds_raw + UNI_OFF;
    float* xol = (float*)uni;                       // 32 x 114 floats
    unsigned short* hout = (unsigned short*)(uni + HOUT_OFF);   // 32 x 24 bf16
    int4* stage4 = (int4*)uni;                      // 6kc x 2mi x 64 lanes
    const bf16x8* stage = (const bf16x8*)uni;

    const int tid = threadIdx.x;
    const int lane = tid & 63, wave = tid >> 6;
    const int group = blockIdx.x & 7, member = blockIdx.x >> 3;
    const int b0 = group * 32;
    const int ni0 = wave, ni1 = wave + 4;
    const bool has1 = (ni1 < NFR);

    // one-time: weights + bias into LDS
    {
        const int4* src = (const int4*)(Wf + (size_t)member * (NKC * NFR * 64 * 8));
        for (int i = tid; i < W_LDS / 16; i += 256) ((int4*)Wl)[i] = src[i];
        if (tid < PCOLS) biasL[tid] = biasP[member * PCOLS + tid];
    }
    __syncthreads();

    const float bias_a = biasL[ni0 * 16 + (lane & 15)];
    const float bias_b = has1 ? biasL[ni1 * 16 + (lane & 15)] : 0.f;

    // staging slot geometry (3 slots per thread per phase)
    int s_kcl[3], s_mi[3], s_ln[3];
    const unsigned short* s_src[3];
    #pragma unroll
    for (int i = 0; i < 3; ++i) {
        int s = tid + 256 * i;                       // < 768
        s_kcl[i] = s >> 7; s_mi[i] = (s >> 6) & 1; s_ln[i] = s & 63;
        int b = b0 + s_mi[i] * 16 + (s_ln[i] & 15);
        int h0i = s_kcl[i] * 32 + ((s_ln[i] >> 4) & 3) * 8;
        s_src[i] = hbf + (size_t)b * H_ + h0i;      // add t-offset later
    }

    float c_r[3] = {0.f, 0.f, 0.f};
    unsigned* gflags = flags + group * NMEM;

    for (int t = 0; t < T_; ++t) {
        // prefetch x A-frags (independent of recurrence)
        bf16x8 xf[8][2];
        #pragma unroll
        for (int kc = 0; kc < 8; ++kc)
            #pragma unroll
            for (int mi = 0; mi < 2; ++mi)
                xf[kc][mi] = *((const bf16x8*)(xA
                    + ((((size_t)t * 8 + kc) * 8 + group) * 2 + mi) * 512 + lane * 8));

        // ---- wait for group's step t-1 h publication ----
        if (t > 0) {
            if (tid < NMEM) {
                const unsigned tgt = (unsigned)t;
                while (__hip_atomic_load(gflags + tid, __ATOMIC_RELAXED,
                                         __HIP_MEMORY_SCOPE_AGENT) < tgt)
                    __builtin_amdgcn_s_sleep(1);
            }
            __syncthreads();
        }

        // ---- issue ALL h loads (both halves) ----
        unsigned long long la[3][2], lb[3][2];
        if (t > 0) {
            const size_t toff = (size_t)(t - 1) * B_ * H_;
            #pragma unroll
            for (int i = 0; i < 3; ++i) {
                const unsigned long long* pa = (const unsigned long long*)(s_src[i] + toff);
                const unsigned long long* pb = (const unsigned long long*)(s_src[i] + toff + 192);
                la[i][0] = __hip_atomic_load(pa, __ATOMIC_RELAXED, __HIP_MEMORY_SCOPE_AGENT);
                la[i][1] = __hip_atomic_load(pa + 1, __ATOMIC_RELAXED, __HIP_MEMORY_SCOPE_AGENT);
                lb[i][0] = __hip_atomic_load(pb, __ATOMIC_RELAXED, __HIP_MEMORY_SCOPE_AGENT);
                lb[i][1] = __hip_atomic_load(pb + 1, __ATOMIC_RELAXED, __HIP_MEMORY_SCOPE_AGENT);
            }
        }

        // ---- x MFMAs (kc 0..7) while h loads fly ----
        f32x4 acc[2][2];
        #pragma unroll
        for (int mi = 0; mi < 2; ++mi) {
            acc[mi][0] = f32x4{bias_a, bias_a, bias_a, bias_a};
            acc[mi][1] = f32x4{bias_b, bias_b, bias_b, bias_b};
        }
        #pragma unroll
        for (int kc = 0; kc < 8; ++kc) {
            bf16x8 w0 = ((const bf16x8*)Wl)[(kc * NFR + ni0) * 64 + lane];
            acc[0][0] = __builtin_amdgcn_mfma_f32_16x16x32_bf16(xf[kc][0], w0, acc[0][0], 0, 0, 0);
            acc[1][0] = __builtin_amdgcn_mfma_f32_16x16x32_bf16(xf[kc][1], w0, acc[1][0], 0, 0, 0);
            if (has1) {
                bf16x8 w1 = ((const bf16x8*)Wl)[(kc * NFR + ni1) * 64 + lane];
                acc[0][1] = __builtin_amdgcn_mfma_f32_16x16x32_bf16(xf[kc][0], w1, acc[0][1], 0, 0, 0);
                acc[1][1] = __builtin_amdgcn_mfma_f32_16x16x32_bf16(xf[kc][1], w1, acc[1][1], 0, 0, 0);
            }
        }

        if (t > 0) {
            // ---- stage half A (inner kc 8..13) ----
            #pragma unroll
            for (int i = 0; i < 3; ++i)
                stage4[(s_kcl[i] * 2 + s_mi[i]) * 64 + s_ln[i]] =
                    make_int4((int)(la[i][0] & 0xffffffffu), (int)(la[i][0] >> 32),
                              (int)(la[i][1] & 0xffffffffu), (int)(la[i][1] >> 32));
            __syncthreads();
            #pragma unroll
            for (int kcl = 0; kcl < 6; ++kcl) {
                bf16x8 a0 = stage[(kcl * 2 + 0) * 64 + lane];
                bf16x8 a1 = stage[(kcl * 2 + 1) * 64 + lane];
                bf16x8 w0 = ((const bf16x8*)Wl)[((8 + kcl) * NFR + ni0) * 64 + lane];
                acc[0][0] = __builtin_amdgcn_mfma_f32_16x16x32_bf16(a0, w0, acc[0][0], 0, 0, 0);
                acc[1][0] = __builtin_amdgcn_mfma_f32_16x16x32_bf16(a1, w0, acc[1][0], 0, 0, 0);
                if (has1) {
                    bf16x8 w1 = ((const bf16x8*)Wl)[((8 + kcl) * NFR + ni1) * 64 + lane];
                    acc[0][1] = __builtin_amdgcn_mfma_f32_16x16x32_bf16(a0, w1, acc[0][1], 0, 0, 0);
                    acc[1][1] = __builtin_amdgcn_mfma_f32_16x16x32_bf16(a1, w1, acc[1][1], 0, 0, 0);
                }
            }
            __syncthreads();
            // ---- stage half B (inner kc 14..19) ----
            #pragma unroll
            for (int i = 0; i < 3; ++i)
                stage4[(s_kcl[i] * 2 + s_mi[i]) * 64 + s_ln[i]] =
                    make_int4((int)(lb[i][0] & 0xffffffffu), (int)(lb[i][0] >> 32),
                              (int)(lb[i][1] & 0xffffffffu), (int)(lb[i][1] >> 32));
            __syncthreads();
            #pragma unroll
            for (int kcl = 0; kcl < 6; ++kcl) {
                bf16x8 a0 = stage[(kcl * 2 + 0) * 64 + lane];
                bf16x8 a1 = stage[(kcl * 2 + 1) * 64 + lane];
                bf16x8 w0 = ((const bf16x8*)Wl)[((14 + kcl) * NFR + ni0) * 64 + lane];
                acc[0][0] = __builtin_amdgcn_mfma_f32_16x16x32_bf16(a0, w0, acc[0][0], 0, 0, 0);
                acc[1][0] = __builtin_amdgcn_mfma_f32_16x16x32_bf16(a1, w0, acc[1][0], 0, 0, 0);
                if (has1) {
                    bf16x8 w1 = ((const bf16x8*)Wl)[((14 + kcl) * NFR + ni1) * 64 + lane];
                    acc[0][1] = __builtin_amdgcn_mfma_f32_16x16x32_bf16(a0, w1, acc[0][1], 0, 0, 0);
                    acc[1][1] = __builtin_amdgcn_mfma_f32_16x16x32_bf16(a1, w1, acc[1][1], 0, 0, 0);
                }
            }
        }
        __syncthreads();   // stage dead; xol reuses the region

        // ---- write xo slice to LDS ----
        #pragma unroll
        for (int mi = 0; mi < 2; ++mi) {
            int brow = mi * 16 + ((lane >> 4) << 2);
            #pragma unroll
            for (int r = 0; r < 4; ++r)
                xol[(brow + r) * XOLP + ni0 * 16 + (lane & 15)] = acc[mi][0][r];
            if (has1)
                #pragma unroll
                for (int r = 0; r < 4; ++r)
                    xol[(brow + r) * XOLP + ni1 * 16 + (lane & 15)] = acc[mi][1][r];
        }
        __syncthreads();

        // ---- gates ----
        #pragma unroll
        for (int r = 0; r < 3; ++r) {
            int item = tid + 256 * r;                // < 768
            int b = item & 31, ch = item >> 5;
            const float* row = xol + b * XOLP;
            float z0 = row[0], z1 = row[1], z2 = row[2];
            float z3 = row[3], z4 = row[4], z5 = row[5];
            float m1 = fmaxf(fmaxf(z0, z1), z2);
            float e0 = expf(z0 - m1), e1 = expf(z1 - m1), e2 = expf(z2 - m1);
            float s1 = e0 + e1 + e2;
            float fm0 = e0 / s1, fm1 = (e0 + e1) / s1;
            float m2 = fmaxf(fmaxf(z3, z4), z5);
            float f3 = expf(z3 - m2), f4 = expf(z4 - m2), f5 = expf(z5 - m2);
            float s2 = f3 + f4 + f5;
            float im1 = (f4 + f5) / s2, im2 = f5 / s2;

            int hh = member * CPM + ch;
            int l = hh >> 7;
            float fm = (l == 0) ? fm0 : (l == 1) ? fm1 : 1.f;
            float im = (l == 0) ? 1.f : (l == 1) ? im1 : im2;

            float fg = sigf(row[6 + ch]);
            float ig = sigf(row[6 + CPM + ch]);
            float og = sigf(row[6 + 2 * CPM + ch]);
            float ci = tanhf(row[6 + 3 * CPM + ch]);

            float cl = c_r[r];
            float ov = fm * im;
            float cn = ov * (fg * cl + ig * ci) + (fm - ov) * cl + (im - ov) * ci;
            float hn = og * tanhf(cn);
            c_r[r] = cn;

            hout[b * CPM + ch] = f2bf(hn);
            if (member == 0 && ch == 0)
                dis[t * B_ + b0 + b] = 1.f - (fm0 + fm1 + 1.f) * (1.f / 3.f);
        }
        __syncthreads();

        // ---- packed h publication (8B relaxed agent stores) ----
        if (tid < 192) {
            int b = tid / 6, jj = tid % 6;
            unsigned long long v = *(const unsigned long long*)&hout[b * CPM + jj * 4];
            __hip_atomic_store(
                (unsigned long long*)(hbf + ((size_t)t * B_ + b0 + b) * H_ + member * CPM + jj * 4),
                v, __ATOMIC_RELAXED, __HIP_MEMORY_SCOPE_AGENT);
        }
        __syncthreads();   // drains vmcnt(0) on every wave -> stores acked at LLC

        if (tid == 0)
            __hip_atomic_store(gflags + member, (unsigned)(t + 1),
                               __ATOMIC_RELAXED, __HIP_MEMORY_SCOPE_AGENT);
    }
}

// ---------------- ld weights ----------------
__global__ void k_ld(const float* __restrict__ dis_all, float* __restrict__ ld_all)
{
    int t = blockIdx.x, b = threadIdx.x;
    float s = 0.f, sk[K_];
    #pragma unroll
    for (int k = 0; k < K_; ++k) {
        int tau = t - (K_ - 1) + k;
        float d = (tau >= 0) ? dis_all[tau * B_ + b] : 0.f;
        s += d; sk[k] = s;
    }
    float m = sk[0];
    #pragma unroll
    for (int k = 1; k < K_; ++k) m = fmaxf(m, sk[k]);
    float sum = 0.f;
    #pragma unroll
    for (int k = 0; k < K_; ++k) { sk[k] = expf(sk[k] - m); sum += sk[k]; }
    float inv = 1.f / sum;
    #pragma unroll
    for (int k = 0; k < K_; ++k)
        ld_all[((size_t)t * B_ + b) * K_ + k] = sk[k] * inv;
}

// ---------------- conv via MFMA ----------------
__global__ __launch_bounds__(256)
void k_conv(const unsigned short* __restrict__ hbf, const float* __restrict__ ld_all,
            const unsigned short* __restrict__ Wg, float* __restrict__ out_part)
{
    __shared__ unsigned short Al[64][40];
    __shared__ unsigned short Bl[384][40];
    __shared__ float ldl[64][10];
    const int b0 = blockIdx.x * 64;
    const int t  = blockIdx.y;
    const int tid = threadIdx.x;
    const int wave = tid >> 6, lane = tid & 63;

    for (int idx = tid; idx < 64 * K_; idx += 256)
        ldl[idx / K_][idx % K_] = ld_all[((size_t)t * B_ + b0 + idx / K_) * K_ + idx % K_];
    __syncthreads();

    f32x4 acc[4][6] = {};
    const int arow = tid & 63, ahalf = tid >> 6;

    for (int ch = 0; ch < 120; ++ch) {
        int k = ch / 12, h0 = (ch % 12) * 32;
        int tau = t - (K_ - 1) + k;
        {
            int4 pk;
            if (tau >= 0) {
                float l = ldl[arow][k];
                const unsigned short* hp =
                    hbf + ((size_t)tau * B_ + b0 + arow) * H_ + h0 + ahalf * 8;
                int4 v = *(const int4*)hp;
                unsigned vv[4] = {(unsigned)v.x, (unsigned)v.y, (unsigned)v.z, (unsigned)v.w};
                unsigned out[4];
                #pragma unroll
                for (int q = 0; q < 4; ++q) {
                    float flo = __uint_as_float(vv[q] << 16) * l;
                    float fhi = __uint_as_float(vv[q] & 0xffff0000u) * l;
                    out[q] = (unsigned)f2bf(flo) | ((unsigned)f2bf(fhi) << 16);
                }
                pk = make_int4((int)out[0], (int)out[1], (int)out[2], (int)out[3]);
            } else {
                pk = make_int4(0, 0, 0, 0);
            }
            *(int4*)&Al[arow][ahalf * 8] = pk;
        }
        #pragma unroll
        for (int q = 0; q < 6; ++q) {
            int idx = q * 256 + tid;
            int row = idx >> 2, half = idx & 3;
            const unsigned short* wp = Wg + (size_t)row * 3840 + ch * 32 + half * 8;
            *(int4*)&Bl[row][half * 8] = *(const int4*)wp;
        }
        __syncthreads();

        bf16x8 af[4];
        #pragma unroll
        for (int mi = 0; mi < 4; ++mi)
            af[mi] = *(const bf16x8*)&Al[mi * 16 + (lane & 15)][(lane >> 4) * 8];
        #pragma unroll
        for (int ni = 0; ni < 6; ++ni) {
            bf16x8 bfv = *(const bf16x8*)&Bl[wave * 96 + ni * 16 + (lane & 15)][(lane >> 4) * 8];
            #pragma unroll
            for (int mi = 0; mi < 4; ++mi)
                acc[mi][ni] = __builtin_amdgcn_mfma_f32_16x16x32_bf16(af[mi], bfv, acc[mi][ni], 0, 0, 0);
        }
        __syncthreads();
    }
    #pragma unroll
    for (int mi = 0; mi < 4; ++mi) {
        #pragma unroll
        for (int ni = 0; ni < 6; ++ni) {
            int o = wave * 96 + ni * 16 + (lane & 15);
            int brow = b0 + mi * 16 + ((lane >> 4) << 2);
            #pragma unroll
            for (int r = 0; r < 4; ++r)
                out_part[((size_t)(brow + r) * T_ + t) * H_ + o] = acc[mi][ni][r];
        }
    }
}

// ---------------- theme + combine ----------------
__global__ __launch_bounds__(256)
void k_theme(const unsigned short* __restrict__ hbf, const float* __restrict__ ld_all,
             const float* __restrict__ Ws, const float* __restrict__ bs,
             const float* __restrict__ Wrs, const float* __restrict__ brs,
             const float* __restrict__ bc, float* __restrict__ out_part)
{
    __shared__ float hbar[32][385];
    __shared__ float us[32][65];
    __shared__ float ldl[32][10];
    const int b0 = blockIdx.x * 32, t = blockIdx.y, tid = threadIdx.x;

    for (int idx = tid; idx < 32 * K_; idx += 256)
        ldl[idx / K_][idx % K_] = ld_all[((size_t)t * B_ + b0 + idx / K_) * K_ + idx % K_];
    __syncthreads();

    for (int idx = tid; idx < 32 * H_; idx += 256) {
        int bb = idx / H_, h = idx % H_;
        float s = 0.f;
        #pragma unroll
        for (int k = 0; k < K_; ++k) {
            int tau = t - (K_ - 1) + k;
            if (tau >= 0)
                s += ldl[bb][k] * bf2f(hbf[((size_t)tau * B_ + b0 + bb) * H_ + h]);
        }
        hbar[bb][h] = s * (1.f / K_);
    }
    __syncthreads();

    for (int idx = tid; idx < 32 * HS_; idx += 256) {
        int bb = idx >> 6, jj = idx & 63;
        float s = bs[jj];
        for (int h = 0; h < H_; ++h) s = fmaf(hbar[bb][h], Ws[h * HS_ + jj], s);
        us[bb][jj] = fmaxf(s, 0.f);
    }
    __syncthreads();

    for (int idx = tid; idx < 32 * H_; idx += 256) {
        int bb = idx / H_, o = idx % H_;
        float s = brs[o];
        #pragma unroll
        for (int jj = 0; jj < HS_; ++jj) s = fmaf(us[bb][jj], Wrs[jj * H_ + o], s);
        float th = sigf(s);
        size_t gi = ((size_t)(b0 + bb) * T_ + t) * H_ + o;
        out_part[gi] = bf2f(hbf[((size_t)t * B_ + b0 + bb) * H_ + o])
                     + th * (out_part[gi] + bc[o]);
    }
}

// ---------------- last_output gather ----------------
__global__ void k_last(const int* __restrict__ len_i, const float* __restrict__ out_part,
                       float* __restrict__ last)
{
    int b = blockIdx.x, tid = threadIdx.x;
    bool is64 = (len_i[1] == 0);
    long long v = is64 ? ((const long long*)len_i)[b] : (long long)len_i[b];
    int idx = (int)v;
    idx = max(1, min(T_, idx)) - 1;
    last[(size_t)b * H_ + tid] = out_part[((size_t)b * T_ + idx) * H_ + tid];
}

extern "C" void kernel_launch(void* const* d_in, const int* in_sizes, int n_in,
                              void* d_out, int out_size, void* d_ws, size_t ws_size,
                              hipStream_t stream) {
    const float* x   = (const float*)d_in[0];
    const int*   len = (const int*)d_in[1];
    const float* Wk  = (const float*)d_in[2];
    const float* bk  = (const float*)d_in[3];
    const float* Wr  = (const float*)d_in[4];
    const float* br  = (const float*)d_in[5];
    const float* Ws  = (const float*)d_in[6];
    const float* bs  = (const float*)d_in[7];
    const float* Wrs = (const float*)d_in[8];
    const float* brs = (const float*)d_in[9];
    const float* Wc  = (const float*)d_in[10];
    const float* bc  = (const float*)d_in[11];

    float* out      = (float*)d_out;
    float* last     = out;
    float* out_part = out + (size_t)B_ * H_;

    // workspace layout (bytes), total ~92 MB
    char* p = (char*)d_ws;
    unsigned*       flags  = (unsigned*)p;       p += 1024;
    float*          dis    = (float*)p;          p += (size_t)T_ * B_ * 4;          // 262144
    float*          ld     = (float*)p;          p += (size_t)T_ * B_ * K_ * 4;     // 2621440
    unsigned short* xA     = (unsigned short*)p; p += (size_t)T_ * B_ * D_ * 2;     // 33554432
    unsigned short* WfragG = (unsigned short*)p; p += (size_t)NMEM * NKC * NFR * 64 * 8 * 2; // 2293760
    float*          biasP  = (float*)p;          p += (size_t)NMEM * PCOLS * 4;     // 7168
    unsigned short* hbf    = (unsigned short*)p; p += (size_t)T_ * B_ * H_ * 2;     // 50331648
    unsigned short* Wg     = (unsigned short*)p; p += (size_t)H_ * K_ * H_ * 2;     // 2949120

    k_zero <<<1, 256, 0, stream>>>((float*)flags, 256);
    k_xa   <<<8192, 256, 0, stream>>>(x, xA);
    k_wfrag<<<(NMEM * NKC * NFR * 64 + 255) / 256, 256, 0, stream>>>(Wk, Wr, WfragG);
    k_bias <<<(NMEM * PCOLS + 255) / 256, 256, 0, stream>>>(Wk, bk, Wr, br, biasP);
    k_wg   <<<(H_ * K_ * H_ + 255) / 256, 256, 0, stream>>>(Wc, Wg);

    hipFuncSetAttribute((const void*)k_serial,
                        hipFuncAttributeMaxDynamicSharedMemorySize, LDS_BYTES);
    k_serial<<<NGRP * NMEM, 256, LDS_BYTES, stream>>>(xA, WfragG, biasP, hbf, dis, flags);

    k_ld   <<<T_, B_, 0, stream>>>(dis, ld);
    k_conv <<<dim3(4, T_), 256, 0, stream>>>(hbf, ld, Wg, out_part);
    k_theme<<<dim3(8, T_), 256, 0, stream>>>(hbf, ld, Ws, bs, Wrs, brs, bc, out_part);
    k_last <<<B_, H_, 0, stream>>>(len, out_part, last);
}